// Round 13
// baseline (674.421 us; speedup 1.0000x reference)
//
#include <hip/hip_runtime.h>
#include <stdint.h>
#include <math.h>

#define N_ROWS 16384
#define D_DIM  4096
#define E_EXP  128
#define TAU    2.0e-2f

typedef short  short8 __attribute__((ext_vector_type(8)));
typedef float  f32x4  __attribute__((ext_vector_type(4)));

#define GAS __attribute__((address_space(1)))
#define LAS __attribute__((address_space(3)))

__device__ __forceinline__ void g2lds16(const float* g, uint8_t* l) {
  __builtin_amdgcn_global_load_lds((const GAS uint32_t*)g, (LAS uint32_t*)l, 16, 0, 0);
}

__device__ __forceinline__ uint32_t bf16_rne(float f) {
  uint32_t u = __builtin_bit_cast(uint32_t, f);
  return (u + 0x7fffu + ((u >> 16) & 1u)) >> 16;
}

// ---------------- kernel 0: split W into bf16 hi/lo, FRAGMENT-TILED (proven) --------
// blk = (eg8*128 + kc)*2 + hl ; lane l: W[eg8*16+(l&15)][kc*32+(l>>4)*8 ..+8]
__global__ __launch_bounds__(256) void k0_split(const float* __restrict__ W,
                                                uint16_t* __restrict__ wt) {
  const int b  = blockIdx.x;
  const int t  = threadIdx.x;
  const int eg  = b >> 5;
  const int kcg = b & 31;
  const int kc  = kcg * 4 + (t >> 6);
  const int lane = t & 63;
  const int e  = eg * 16 + (lane & 15);
  const int k0 = kc * 32 + (lane >> 4) * 8;

  const float* src = W + (size_t)e * D_DIM + k0;
  f32x4 w0 = *(const f32x4*)src;
  f32x4 w1 = *(const f32x4*)(src + 4);
  float wf[8] = {w0[0], w0[1], w0[2], w0[3], w1[0], w1[1], w1[2], w1[3]};

  uint16_t h[8], l[8];
  #pragma unroll
  for (int j = 0; j < 8; ++j) {
    uint32_t hh = bf16_rne(wf[j]);
    float hf = __builtin_bit_cast(float, hh << 16);
    h[j] = (uint16_t)hh;
    l[j] = (uint16_t)bf16_rne(wf[j] - hf);
  }
  const size_t blkh = ((size_t)(eg * 128 + kc) * 2 + 0) * 512;
  const size_t blkl = ((size_t)(eg * 128 + kc) * 2 + 1) * 512;
  *(short8*)(wt + blkh + lane * 8) = *(const short8*)h;
  *(short8*)(wt + blkl + lane * 8) = *(const short8*)l;
}

// ---------------- kernel 0x: tile x -> bf16 fragment layout ----------------
// frag idx = rt16*128 + kc ; lane l: x[rt16*16+(l&15)][kc*32+(l>>4)*8 ..+8] (bf16)
// grid 4096 = 1024 rt16 x 4 khalf(1024k each); 512 threads; LDS 64KB raw f32.
__global__ __launch_bounds__(512) void k0x_tile(const float* __restrict__ x,
                                                uint16_t* __restrict__ tx) {
  __shared__ __align__(16) uint8_t smem[65536];
  float* Lx = (float*)smem;                     // [16][1024]

  const int bid  = blockIdx.x;
  const int rt16 = bid >> 2;
  const int kh   = bid & 3;
  const int t    = threadIdx.x;

  // phase 1: coalesced gl_lds: slice i covers rows i*2+(t>>8), k (t&255)*4
  const int prow = t >> 8, pk = (t & 255) * 4;
  #pragma unroll
  for (int i = 0; i < 8; ++i) {
    const float* src = x + (size_t)(rt16 * 16 + i * 2 + prow) * D_DIM + kh * 1024 + pk;
    g2lds16(src, smem + i * 8192 + t * 16);
  }
  asm volatile("s_waitcnt vmcnt(0)" ::: "memory");
  __syncthreads();

  // phase 2: convert + write frags. fi = t>>4 (32 frags), sub = t&15, 4 lanes each.
  const int fi = t >> 4, sub = t & 15;
  const size_t fragbase = ((size_t)rt16 * 128 + kh * 32 + fi) * 512;
  #pragma unroll
  for (int i = 0; i < 4; ++i) {
    const int li  = sub * 4 + i;
    const int row = li & 15, kg = li >> 4;
    const float* rp = Lx + row * 1024 + fi * 32 + kg * 8;
    f32x4 a = *(const f32x4*)rp;
    f32x4 b = *(const f32x4*)(rp + 4);
    uint16_t h[8];
    h[0] = (uint16_t)bf16_rne(a[0]); h[1] = (uint16_t)bf16_rne(a[1]);
    h[2] = (uint16_t)bf16_rne(a[2]); h[3] = (uint16_t)bf16_rne(a[3]);
    h[4] = (uint16_t)bf16_rne(b[0]); h[5] = (uint16_t)bf16_rne(b[1]);
    h[6] = (uint16_t)bf16_rne(b[2]); h[7] = (uint16_t)bf16_rne(b[3]);
    *(short8*)(tx + fragbase + li * 8) = *(const short8*)h;
  }
}

// ---------------- kernel 1: barrier-free flat MFMA GEMM -> logits ----------------
// 256 blocks x 8 waves; wave = 32 rows x 32 experts, K=4096 flat.
__global__ __launch_bounds__(512) void k1_main(
    const uint16_t* __restrict__ tx, const uint16_t* __restrict__ wt,
    float* __restrict__ lg)
{
  const int t    = threadIdx.x;
  const int lane = t & 63;
  const int wv   = __builtin_amdgcn_readfirstlane(t >> 6);
  const int wj   = blockIdx.x * 8 + wv;        // 0..2047
  const int rt   = wj >> 2;                    // 32-row tile 0..511
  const int eq   = wj & 3;                     // expert quarter

  const short8* X8 = (const short8*)tx;
  const short8* W8 = (const short8*)wt;
  const size_t xb0 = ((size_t)(rt * 2 + 0) * 128) * 64 + lane;
  const size_t xb1 = ((size_t)(rt * 2 + 1) * 128) * 64 + lane;
  const size_t wb0 = ((size_t)((eq * 2 + 0) * 128) * 2) * 64 + lane;
  const size_t wb1 = ((size_t)((eq * 2 + 1) * 128) * 2) * 64 + lane;

  f32x4 acc[2][2] = {};

  #pragma unroll 4
  for (int kc = 0; kc < 128; ++kc) {
    short8 a0  = X8[xb0 + (size_t)kc * 64];
    short8 a1  = X8[xb1 + (size_t)kc * 64];
    short8 bh0 = W8[wb0 + (size_t)(kc * 2 + 0) * 64];
    short8 bl0 = W8[wb0 + (size_t)(kc * 2 + 1) * 64];
    short8 bh1 = W8[wb1 + (size_t)(kc * 2 + 0) * 64];
    short8 bl1 = W8[wb1 + (size_t)(kc * 2 + 1) * 64];
    acc[0][0] = __builtin_amdgcn_mfma_f32_16x16x32_bf16(a0, bh0, acc[0][0], 0, 0, 0);
    acc[0][0] = __builtin_amdgcn_mfma_f32_16x16x32_bf16(a0, bl0, acc[0][0], 0, 0, 0);
    acc[0][1] = __builtin_amdgcn_mfma_f32_16x16x32_bf16(a0, bh1, acc[0][1], 0, 0, 0);
    acc[0][1] = __builtin_amdgcn_mfma_f32_16x16x32_bf16(a0, bl1, acc[0][1], 0, 0, 0);
    acc[1][0] = __builtin_amdgcn_mfma_f32_16x16x32_bf16(a1, bh0, acc[1][0], 0, 0, 0);
    acc[1][0] = __builtin_amdgcn_mfma_f32_16x16x32_bf16(a1, bl0, acc[1][0], 0, 0, 0);
    acc[1][1] = __builtin_amdgcn_mfma_f32_16x16x32_bf16(a1, bh1, acc[1][1], 0, 0, 0);
    acc[1][1] = __builtin_amdgcn_mfma_f32_16x16x32_bf16(a1, bl1, acc[1][1], 0, 0, 0);
  }

  // epilogue: C mapping col=lane&15 (expert), row=(lane>>4)*4+i (proven)
  const int ggr = lane >> 4, ccol = lane & 15;
  #pragma unroll
  for (int rg = 0; rg < 2; ++rg)
    #pragma unroll
    for (int egi = 0; egi < 2; ++egi)
      #pragma unroll
      for (int i = 0; i < 4; ++i) {
        int row = rt * 32 + rg * 16 + ggr * 4 + i;
        int e   = eq * 32 + egi * 16 + ccol;
        lg[(size_t)row * E_EXP + e] = acc[rg][egi][i];
      }
}

// ---------------- kernel 3: bias + top-3 + flags + sigmoid out ----------------
__global__ __launch_bounds__(512) void k3_reduce(
    const float* __restrict__ lg, const float* __restrict__ bias,
    float* __restrict__ out, int* __restrict__ flags)
{
  const int t = threadIdx.x;
  const int row = t >> 4, prt = t & 15;     // 32 rows/block, 16 threads/row
  const int grow = blockIdx.x * 32 + row;
  const float* pp = lg + (size_t)grow * E_EXP + prt * 8;

  f32x4 a = *(const f32x4*)pp;
  f32x4 b = *(const f32x4*)(pp + 4);
  float lv[8] = {a[0], a[1], a[2], a[3], b[0], b[1], b[2], b[3]};

  float l1 = -3e38f, l2 = -3e38f, l3 = -3e38f;
  int   i1 = -1, i2 = -1, i3 = -1;
  auto ins = [&](float v, int e) {
    if (v > l1 || (v == l1 && e < i1)) { l3=l2; i3=i2; l2=l1; i2=i1; l1=v; i1=e; }
    else if (v > l2 || (v == l2 && e < i2)) { l3=l2; i3=i2; l2=v; i2=e; }
    else if (v > l3 || (v == l3 && e < i3)) { l3=v; i3=e; }
  };
  #pragma unroll
  for (int j = 0; j < 8; ++j) {
    int e = prt * 8 + j;
    ins(lv[j] + bias[e], e);
  }
  #pragma unroll
  for (int m = 1; m <= 8; m <<= 1) {
    float a1 = __shfl_xor(l1, m), a2 = __shfl_xor(l2, m), a3 = __shfl_xor(l3, m);
    int   b1i = __shfl_xor(i1, m), b2i = __shfl_xor(i2, m), b3i = __shfl_xor(i3, m);
    ins(a1, b1i); ins(a2, b2i); ins(a3, b3i);
  }
  if (prt == 0) {
    int fl = ((l1 - l2) < TAU) || ((l2 - l3) < TAU);
    flags[grow] = fl;
    out[(size_t)grow * 2 + 0] = 1.f / (1.f + __expf(-l1));
    out[(size_t)grow * 2 + 1] = 1.f / (1.f + __expf(-l2));
    out[(size_t)N_ROWS * 2 + (size_t)grow * 2 + 0] = (float)i1;
    out[(size_t)N_ROWS * 2 + (size_t)grow * 2 + 1] = (float)i2;
  }
}

// ---------------- kernel 2: exact f64 fixup for flagged rows (proven) ----------------
__global__ __launch_bounds__(1024) void k2_fix(
    const float* __restrict__ x, const float* __restrict__ W,
    const float* __restrict__ bias, const int* __restrict__ flags,
    float* __restrict__ out)
{
  __shared__ double lgs[E_EXP];
  const int t    = threadIdx.x;        // 1024 threads = 16 waves
  const int wvi  = t >> 6, lane = t & 63;
  const int e    = wvi * 8 + (lane >> 3);
  const int sub  = lane & 7;
  const int rbase = blockIdx.x * 4;

  for (int rr = 0; rr < 4; ++rr) {
    const int row = rbase + rr;
    if (!flags[row]) continue;
    const float* xr = x + (size_t)row * D_DIM;
    const float* wr = W + (size_t)e * D_DIM;
    double a0 = 0.0, a1 = 0.0, a2 = 0.0, a3 = 0.0;
    for (int j = 0; j < 128; ++j) {
      const int c4 = (j * 8 + sub) * 4;
      f32x4 xv = *(const f32x4*)(xr + c4);
      f32x4 wvv = *(const f32x4*)(wr + c4);
      a0 += (double)xv[0] * wvv[0];
      a1 += (double)xv[1] * wvv[1];
      a2 += (double)xv[2] * wvv[2];
      a3 += (double)xv[3] * wvv[3];
    }
    double acc = (a0 + a1) + (a2 + a3);
    #pragma unroll
    for (int m = 1; m <= 4; m <<= 1) acc += __shfl_xor(acc, m);
    if (sub == 0) lgs[e] = acc + (double)bias[e];
    __syncthreads();
    if (t == 0) {
      double l1 = -1e300, l2 = -1e300; int i1 = -1, i2 = -1;
      for (int ee = 0; ee < E_EXP; ++ee) {
        double v = lgs[ee];
        if (v > l1) { l2 = l1; i2 = i1; l1 = v; i1 = ee; }
        else if (v > l2) { l2 = v; i2 = ee; }
      }
      out[(size_t)row * 2 + 0] = (float)(1.0 / (1.0 + exp(-l1)));
      out[(size_t)row * 2 + 1] = (float)(1.0 / (1.0 + exp(-l2)));
      out[(size_t)N_ROWS * 2 + (size_t)row * 2 + 0] = (float)i1;
      out[(size_t)N_ROWS * 2 + (size_t)row * 2 + 1] = (float)i2;
    }
    __syncthreads();
  }
}

extern "C" void kernel_launch(void* const* d_in, const int* in_sizes, int n_in,
                              void* d_out, int out_size, void* d_ws, size_t ws_size,
                              hipStream_t stream) {
  const float* x  = (const float*)d_in[0];
  const float* Wm = (const float*)d_in[1];
  const float* b  = (const float*)d_in[2];
  float* out = (float*)d_out;

  uint8_t* ws = (uint8_t*)d_ws;
  uint16_t* wt    = (uint16_t*)ws;                               // 2 MiB tiled W
  int*      flags = (int*)(ws + 2u * 1024 * 1024);               // 64 KiB
  uint16_t* tx    = (uint16_t*)(ws + 4u * 1024 * 1024);          // 128 MiB tiled x
  float*    lgts  = (float*)(ws + 4u * 1024 * 1024 + 134217728u);// 8 MiB logits

  k0_split<<<dim3(256), dim3(256), 0, stream>>>(Wm, wt);
  k0x_tile<<<dim3(4096), dim3(512), 0, stream>>>(x, tx);
  k1_main<<<dim3(256), dim3(512), 0, stream>>>(tx, wt, lgts);
  k3_reduce<<<dim3(N_ROWS / 32), dim3(512), 0, stream>>>(lgts, b, out, flags);
  k2_fix<<<dim3(N_ROWS / 4), dim3(1024), 0, stream>>>(x, Wm, b, flags, out);
}

// Round 14
// 315.320 us; speedup vs baseline: 2.1388x; 2.1388x over previous
//
#include <hip/hip_runtime.h>
#include <stdint.h>
#include <math.h>

#define N_ROWS 16384
#define D_DIM  4096
#define E_EXP  128
#define KSPLIT 4
#define KCHUNK (D_DIM / KSPLIT)  // 1024
#define NKC    (KCHUNK / 32)     // 32 k-chunks of 32 per wave
#define TAU    2.5e-4f

typedef short  short8 __attribute__((ext_vector_type(8)));
typedef float  f32x4  __attribute__((ext_vector_type(4)));

__device__ __forceinline__ uint32_t bf16_rne(float f) {
  uint32_t u = __builtin_bit_cast(uint32_t, f);
  return (u + 0x7fffu + ((u >> 16) & 1u)) >> 16;
}

// ---------------- kernel 0: split W into bf16 hi/lo, FRAGMENT-TILED (proven) --------
// blk = (eg*128 + kc)*2 + hl ; lane l: W[eg*16+(l&15)][kc*32+(l>>4)*8 ..+8]
__global__ __launch_bounds__(256) void k0_split(const float* __restrict__ W,
                                                uint16_t* __restrict__ wt) {
  const int b  = blockIdx.x;
  const int t  = threadIdx.x;
  const int eg  = b >> 5;
  const int kcg = b & 31;
  const int kc  = kcg * 4 + (t >> 6);
  const int lane = t & 63;
  const int e  = eg * 16 + (lane & 15);
  const int k0 = kc * 32 + (lane >> 4) * 8;

  const float* src = W + (size_t)e * D_DIM + k0;
  f32x4 w0 = *(const f32x4*)src;
  f32x4 w1 = *(const f32x4*)(src + 4);
  float wf[8] = {w0[0], w0[1], w0[2], w0[3], w1[0], w1[1], w1[2], w1[3]};

  uint16_t h[8], l[8];
  #pragma unroll
  for (int j = 0; j < 8; ++j) {
    uint32_t hh = bf16_rne(wf[j]);
    float hf = __builtin_bit_cast(float, hh << 16);
    h[j] = (uint16_t)hh;
    l[j] = (uint16_t)bf16_rne(wf[j] - hf);
  }
  const size_t blkh = ((size_t)(eg * 128 + kc) * 2 + 0) * 512;
  const size_t blkl = ((size_t)(eg * 128 + kc) * 2 + 1) * 512;
  *(short8*)(wt + blkh + lane * 8) = *(const short8*)h;
  *(short8*)(wt + blkl + lane * 8) = *(const short8*)l;
}

// ---------------- kernel 1: barrier-free flat split-bf16 MFMA -> f32 partials ------
// 512 blocks = 128 row-groups x 4 k-chunks; 8 waves/block; wave = 16 rows x 128 e.
// No LDS, no barriers: x loaded frag-direct, converted in-register.
__global__ __launch_bounds__(512, 4) void k1_main(
    const float* __restrict__ x, const uint16_t* __restrict__ wt,
    float* __restrict__ part)
{
  const int t    = threadIdx.x;
  const int lane = t & 63;
  const int wv   = __builtin_amdgcn_readfirstlane(t >> 6);
  const int rg   = blockIdx.x >> 2;      // 0..127
  const int kh   = blockIdx.x & 3;       // 0..3
  const int row0 = rg * 128 + wv * 16;
  const int r15  = lane & 15, kg = lane >> 4;

  const float* xp = x + (size_t)(row0 + r15) * D_DIM + kh * KCHUNK + kg * 8;
  const short8* W8 = (const short8*)wt;

  f32x4 acc[8] = {};

  #pragma unroll 2
  for (int kc = 0; kc < NKC; ++kc) {
    // x frag-direct load: lane holds x[row0+r15][k .. k+8) raw f32
    f32x4 a = *(const f32x4*)(xp + kc * 32);
    f32x4 b = *(const f32x4*)(xp + kc * 32 + 4);
    float xf[8] = {a[0], a[1], a[2], a[3], b[0], b[1], b[2], b[3]};

    // convert to bf16 hi/lo fragments in-register
    uint32_t hpk[4], lpk[4];
    #pragma unroll
    for (int j = 0; j < 4; ++j) {
      uint32_t h0 = bf16_rne(xf[2*j]), h1 = bf16_rne(xf[2*j+1]);
      float h0f = __builtin_bit_cast(float, h0 << 16);
      float h1f = __builtin_bit_cast(float, h1 << 16);
      uint32_t l0 = bf16_rne(xf[2*j] - h0f), l1 = bf16_rne(xf[2*j+1] - h1f);
      hpk[j] = h0 | (h1 << 16);
      lpk[j] = l0 | (l1 << 16);
    }
    short8 ah = __builtin_bit_cast(short8, *(uint4*)hpk);
    short8 al = __builtin_bit_cast(short8, *(uint4*)lpk);

    const int kcg = kh * NKC + kc;       // global k-chunk 0..127
    #pragma unroll
    for (int eg = 0; eg < 8; ++eg) {
      const size_t bb = ((size_t)(eg * 128 + kcg) * 2) * 64 + lane;
      short8 bh = W8[bb];
      short8 bl = W8[bb + 64];
      acc[eg] = __builtin_amdgcn_mfma_f32_16x16x32_bf16(ah, bh, acc[eg], 0, 0, 0);
      acc[eg] = __builtin_amdgcn_mfma_f32_16x16x32_bf16(al, bh, acc[eg], 0, 0, 0);
      acc[eg] = __builtin_amdgcn_mfma_f32_16x16x32_bf16(ah, bl, acc[eg], 0, 0, 0);
    }
  }

  // epilogue: partial[kh][row0 + kg*4 + i][eg*16 + r15] = acc[eg][i]
  float* dst = part + ((size_t)kh * N_ROWS + row0) * E_EXP;
  #pragma unroll
  for (int eg = 0; eg < 8; ++eg)
    #pragma unroll
    for (int i = 0; i < 4; ++i) {
      int rl = kg * 4 + i;
      dst[(size_t)rl * E_EXP + eg * 16 + r15] = acc[eg][i];
    }
}

// ---------------- kernel 3: reduce partials + bias + top-3 + flags (proven R10) ----
__global__ __launch_bounds__(512) void k3_reduce(
    const float* __restrict__ part, const float* __restrict__ bias,
    float* __restrict__ out, int* __restrict__ flags)
{
  const int t = threadIdx.x;
  const int row = t >> 4, prt = t & 15;     // 32 rows/block, 16 threads/row
  const int grow = blockIdx.x * 32 + row;
  const float* pp = part + (size_t)grow * E_EXP + prt * 8;

  f32x4 s0 = {}, s1 = {};
  #pragma unroll
  for (int ks = 0; ks < KSPLIT; ++ks) {
    const float* q = pp + (size_t)ks * N_ROWS * E_EXP;
    f32x4 a = *(const f32x4*)q;
    f32x4 b = *(const f32x4*)(q + 4);
    s0 += a; s1 += b;
  }
  float lv[8] = {s0[0], s0[1], s0[2], s0[3], s1[0], s1[1], s1[2], s1[3]};

  float l1 = -3e38f, l2 = -3e38f, l3 = -3e38f;
  int   i1 = -1, i2 = -1, i3 = -1;
  auto ins = [&](float v, int e) {
    if (v > l1 || (v == l1 && e < i1)) { l3=l2; i3=i2; l2=l1; i2=i1; l1=v; i1=e; }
    else if (v > l2 || (v == l2 && e < i2)) { l3=l2; i3=i2; l2=v; i2=e; }
    else if (v > l3 || (v == l3 && e < i3)) { l3=v; i3=e; }
  };
  #pragma unroll
  for (int j = 0; j < 8; ++j) {
    int e = prt * 8 + j;
    ins(lv[j] + bias[e], e);
  }
  #pragma unroll
  for (int m = 1; m <= 8; m <<= 1) {
    float a1 = __shfl_xor(l1, m), a2 = __shfl_xor(l2, m), a3 = __shfl_xor(l3, m);
    int   b1i = __shfl_xor(i1, m), b2i = __shfl_xor(i2, m), b3i = __shfl_xor(i3, m);
    ins(a1, b1i); ins(a2, b2i); ins(a3, b3i);
  }
  if (prt == 0) {
    int fl = ((l1 - l2) < TAU) || ((l2 - l3) < TAU);
    flags[grow] = fl;
    out[(size_t)grow * 2 + 0] = 1.f / (1.f + __expf(-l1));
    out[(size_t)grow * 2 + 1] = 1.f / (1.f + __expf(-l2));
    out[(size_t)N_ROWS * 2 + (size_t)grow * 2 + 0] = (float)i1;
    out[(size_t)N_ROWS * 2 + (size_t)grow * 2 + 1] = (float)i2;
  }
}

// ---------------- kernel 2: exact f64 fixup for flagged rows (proven) ----------------
__global__ __launch_bounds__(1024) void k2_fix(
    const float* __restrict__ x, const float* __restrict__ W,
    const float* __restrict__ bias, const int* __restrict__ flags,
    float* __restrict__ out)
{
  __shared__ double lgs[E_EXP];
  const int t    = threadIdx.x;        // 1024 threads = 16 waves
  const int wvi  = t >> 6, lane = t & 63;
  const int e    = wvi * 8 + (lane >> 3);
  const int sub  = lane & 7;
  const int rbase = blockIdx.x * 8;

  for (int rr = 0; rr < 8; ++rr) {
    const int row = rbase + rr;
    if (!flags[row]) continue;
    const float* xr = x + (size_t)row * D_DIM;
    const float* wr = W + (size_t)e * D_DIM;
    double a0 = 0.0, a1 = 0.0, a2 = 0.0, a3 = 0.0;
    for (int j = 0; j < 128; ++j) {
      const int c4 = (j * 8 + sub) * 4;
      f32x4 xv = *(const f32x4*)(xr + c4);
      f32x4 wvv = *(const f32x4*)(wr + c4);
      a0 += (double)xv[0] * wvv[0];
      a1 += (double)xv[1] * wvv[1];
      a2 += (double)xv[2] * wvv[2];
      a3 += (double)xv[3] * wvv[3];
    }
    double acc = (a0 + a1) + (a2 + a3);
    #pragma unroll
    for (int m = 1; m <= 4; m <<= 1) acc += __shfl_xor(acc, m);
    if (sub == 0) lgs[e] = acc + (double)bias[e];
    __syncthreads();
    if (t == 0) {
      double l1 = -1e300, l2 = -1e300; int i1 = -1, i2 = -1;
      for (int ee = 0; ee < E_EXP; ++ee) {
        double v = lgs[ee];
        if (v > l1) { l2 = l1; i2 = i1; l1 = v; i1 = ee; }
        else if (v > l2) { l2 = v; i2 = ee; }
      }
      out[(size_t)row * 2 + 0] = (float)(1.0 / (1.0 + exp(-l1)));
      out[(size_t)row * 2 + 1] = (float)(1.0 / (1.0 + exp(-l2)));
      out[(size_t)N_ROWS * 2 + (size_t)row * 2 + 0] = (float)i1;
      out[(size_t)N_ROWS * 2 + (size_t)row * 2 + 1] = (float)i2;
    }
    __syncthreads();
  }
}

extern "C" void kernel_launch(void* const* d_in, const int* in_sizes, int n_in,
                              void* d_out, int out_size, void* d_ws, size_t ws_size,
                              hipStream_t stream) {
  const float* x  = (const float*)d_in[0];
  const float* Wm = (const float*)d_in[1];
  const float* b  = (const float*)d_in[2];
  float* out = (float*)d_out;

  uint8_t* ws = (uint8_t*)d_ws;
  uint16_t* wt    = (uint16_t*)ws;                    // 2 MiB tiled W (h+l)
  int*      flags = (int*)(ws + 2u * 1024 * 1024);    // 64 KiB
  float*    part  = (float*)(ws + 4u * 1024 * 1024);  // 32 MiB partials

  k0_split<<<dim3(256), dim3(256), 0, stream>>>(Wm, wt);
  k1_main<<<dim3(128 * KSPLIT), dim3(512), 0, stream>>>(x, wt, part);
  k3_reduce<<<dim3(N_ROWS / 32), dim3(512), 0, stream>>>(part, b, out, flags);
  k2_fix<<<dim3(N_ROWS / 8), dim3(1024), 0, stream>>>(x, Wm, b, flags, out);
}

// Round 15
// 192.249 us; speedup vs baseline: 3.5081x; 1.6402x over previous
//
#include <hip/hip_runtime.h>
#include <stdint.h>
#include <math.h>

#define N_ROWS 16384
#define D_DIM  4096
#define E_EXP  128
#define BM     64
#define BKR    128              // k per round
#define KSPLIT 2
#define KCHUNK (D_DIM / KSPLIT) // 2048
#define NRND   (KCHUNK / BKR)   // 16 rounds
#define TAU    2.5e-4f

typedef short  short8 __attribute__((ext_vector_type(8)));
typedef float  f32x4  __attribute__((ext_vector_type(4)));

__device__ __forceinline__ uint32_t bf16_rne(float f) {
  uint32_t u = __builtin_bit_cast(uint32_t, f);
  return (u + 0x7fffu + ((u >> 16) & 1u)) >> 16;
}

// ---------------- kernel 0: split W into bf16 hi/lo, FRAGMENT-TILED (proven) --------
// blk = (eg8*128 + kc)*2 + hl ; lane l: W[eg8*16+(l&15)][kc*32+(l>>4)*8 ..+8]
__global__ __launch_bounds__(256) void k0_split(const float* __restrict__ W,
                                                uint16_t* __restrict__ wt) {
  const int b  = blockIdx.x;
  const int t  = threadIdx.x;
  const int eg  = b >> 5;
  const int kcg = b & 31;
  const int kc  = kcg * 4 + (t >> 6);
  const int lane = t & 63;
  const int e  = eg * 16 + (lane & 15);
  const int k0 = kc * 32 + (lane >> 4) * 8;

  const float* src = W + (size_t)e * D_DIM + k0;
  f32x4 w0 = *(const f32x4*)src;
  f32x4 w1 = *(const f32x4*)(src + 4);
  float wf[8] = {w0[0], w0[1], w0[2], w0[3], w1[0], w1[1], w1[2], w1[3]};

  uint16_t h[8], l[8];
  #pragma unroll
  for (int j = 0; j < 8; ++j) {
    uint32_t hh = bf16_rne(wf[j]);
    float hf = __builtin_bit_cast(float, hh << 16);
    h[j] = (uint16_t)hh;
    l[j] = (uint16_t)bf16_rne(wf[j] - hf);
  }
  const size_t blkh = ((size_t)(eg * 128 + kc) * 2 + 0) * 512;
  const size_t blkl = ((size_t)(eg * 128 + kc) * 2 + 1) * 512;
  *(short8*)(wt + blkh + lane * 8) = *(const short8*)h;
  *(short8*)(wt + blkl + lane * 8) = *(const short8*)l;
}

// ---------------- kernel 1: BM=64, wave = 32 rows x 32 experts -> f32 partials -----
// 512 blocks = 256 row-tiles x 2 k-halves; 8 waves = 2 row-halves x 4 expert-quarters.
__global__ __launch_bounds__(512, 4) void k1_main(
    const float* __restrict__ x, const uint16_t* __restrict__ wt,
    float* __restrict__ part)
{
  __shared__ __align__(16) uint8_t smem[65536];   // 2 x 32KB frag buffers

  const int t    = threadIdx.x;
  const int lane = t & 63;
  const int wv   = __builtin_amdgcn_readfirstlane(t >> 6);
  const int rh   = wv >> 2;            // row half 0/1
  const int eq   = wv & 3;             // expert quarter 0..3
  const int rt   = blockIdx.x >> 1;    // 0..255
  const int kh   = blockIdx.x & 1;     // 0..1
  const int row0 = rt * BM;
  const int kb0  = kh * KCHUNK;

  // ---- staging map: chunk c in {0,1}: row lr = c*32 + (t>>4), kgroup kg = t&15
  const int lr0 = t >> 4;              // 0..31  (chunk1 row = lr0+32)
  const int kg  = t & 15;
  const float* xp0 = x + (size_t)(row0 + lr0) * D_DIM + kb0 + kg * 8;
  const float* xp1 = xp0 + (size_t)32 * D_DIM;

  // frag write addr: s=kg>>2, gg=kg&3, rr=lr&15 (same for both chunks), rg0=lr0>>4
  const int s_w = kg >> 2, gg_w = kg & 3, rr_w = lr0 & 15, rg0 = lr0 >> 4;
  const int p_w  = gg_w * 16 + (rr_w ^ (gg_w << 1) ^ s_w);
  const int wa0h = (s_w * 8 + rg0 * 2 + 0) * 1024 + p_w * 16;  // chunk0 hi
  // chunk0 lo = +1024 ; chunk1 hi = +4096 ; chunk1 lo = +5120

  // ---- frag read map ----
  const int ggr = lane >> 4, rrr = lane & 15;
  const int p_r0 = ggr * 16 + (rrr ^ (ggr << 1));  // step s: pr = p_r0 ^ s

  const short8* Wt8 = (const short8*)wt;
  const int ccol = lane & 15;

  f32x4 acc[2][2] = {};                // [rg local][egi]

  // x prefetch 2-deep: xa = tile r, xb = tile r+1 (4 f32x4 each)
  f32x4 xa[4], xb[4];
  xa[0] = *((const f32x4*)xp0 + 0); xa[1] = *((const f32x4*)xp0 + 1);
  xa[2] = *((const f32x4*)xp1 + 0); xa[3] = *((const f32x4*)xp1 + 1);
  xb[0] = *((const f32x4*)(xp0 + BKR) + 0); xb[1] = *((const f32x4*)(xp0 + BKR) + 1);
  xb[2] = *((const f32x4*)(xp1 + BKR) + 0); xb[3] = *((const f32x4*)(xp1 + BKR) + 1);

  #pragma unroll 2
  for (int r = 0; r < NRND; ++r) {
    // 1) convert xa (tile r) -> bf16 h/l, write frag buffer buf[r&1]
    uint8_t* buf = smem + (r & 1) * 32768;
    #pragma unroll
    for (int c = 0; c < 2; ++c) {
      float xf[8] = {xa[c*2][0], xa[c*2][1], xa[c*2][2], xa[c*2][3],
                     xa[c*2+1][0], xa[c*2+1][1], xa[c*2+1][2], xa[c*2+1][3]};
      uint32_t hpk[4], lpk[4];
      #pragma unroll
      for (int j = 0; j < 4; ++j) {
        uint32_t h0 = bf16_rne(xf[2*j]), h1 = bf16_rne(xf[2*j+1]);
        float h0f = __builtin_bit_cast(float, h0 << 16);
        float h1f = __builtin_bit_cast(float, h1 << 16);
        uint32_t l0 = bf16_rne(xf[2*j] - h0f), l1 = bf16_rne(xf[2*j+1] - h1f);
        hpk[j] = h0 | (h1 << 16);
        lpk[j] = l0 | (l1 << 16);
      }
      *(uint4*)(buf + wa0h + c * 4096)        = make_uint4(hpk[0], hpk[1], hpk[2], hpk[3]);
      *(uint4*)(buf + wa0h + c * 4096 + 1024) = make_uint4(lpk[0], lpk[1], lpk[2], lpk[3]);
    }

    // 2) rotate x pipeline; issue loads for tile r+2
    #pragma unroll
    for (int q = 0; q < 4; ++q) xa[q] = xb[q];
    if (r + 2 < NRND) {
      const float* n0 = xp0 + (size_t)(r + 2) * BKR;
      const float* n1 = xp1 + (size_t)(r + 2) * BKR;
      xb[0] = *((const f32x4*)n0 + 0); xb[1] = *((const f32x4*)n0 + 1);
      xb[2] = *((const f32x4*)n1 + 0); xb[3] = *((const f32x4*)n1 + 1);
    }

    // 3) LDS writes visible; barrier
    asm volatile("s_waitcnt lgkmcnt(0)" ::: "memory");
    __builtin_amdgcn_s_barrier();

    // 4) MFMA round r: 4 k-steps x 2 egi x 2 rg x {hh, lh, hl}
    #pragma unroll
    for (int s = 0; s < 4; ++s) {
      const int pr = p_r0 ^ s;
      const int kcg = kh * 64 + r * 4 + s;       // global k-chunk-of-32
      #pragma unroll
      for (int egi = 0; egi < 2; ++egi) {
        const int eg8 = eq * 2 + egi;
        const size_t bb = ((size_t)(eg8 * 128 + kcg) * 2) * 64 + lane;
        const short8 bh = Wt8[bb];
        const short8 bl = Wt8[bb + 64];
        #pragma unroll
        for (int rg = 0; rg < 2; ++rg) {
          const int rgg = rh * 2 + rg;
          const uint8_t* fb = buf + (s * 8 + rgg * 2) * 1024 + pr * 16;
          short8 ah = *(const short8*)fb;
          short8 al = *(const short8*)(fb + 1024);
          acc[rg][egi] = __builtin_amdgcn_mfma_f32_16x16x32_bf16(ah, bh, acc[rg][egi], 0, 0, 0);
          acc[rg][egi] = __builtin_amdgcn_mfma_f32_16x16x32_bf16(al, bh, acc[rg][egi], 0, 0, 0);
          acc[rg][egi] = __builtin_amdgcn_mfma_f32_16x16x32_bf16(ah, bl, acc[rg][egi], 0, 0, 0);
        }
      }
    }
  }

  // ---- epilogue: store partials part[kh][row][e] ----
  float* dst = part + ((size_t)kh * N_ROWS + row0) * E_EXP;
  #pragma unroll
  for (int rg = 0; rg < 2; ++rg)
    #pragma unroll
    for (int egi = 0; egi < 2; ++egi)
      #pragma unroll
      for (int i = 0; i < 4; ++i) {
        int rl = (rh * 2 + rg) * 16 + ggr * 4 + i;
        int e  = (eq * 2 + egi) * 16 + ccol;
        dst[(size_t)rl * E_EXP + e] = acc[rg][egi][i];
      }
}

// ---------------- kernel 3: reduce partials + bias + top-3 + flags (proven) --------
__global__ __launch_bounds__(512) void k3_reduce(
    const float* __restrict__ part, const float* __restrict__ bias,
    float* __restrict__ out, int* __restrict__ flags)
{
  const int t = threadIdx.x;
  const int row = t >> 4, prt = t & 15;     // 32 rows/block, 16 threads/row
  const int grow = blockIdx.x * 32 + row;
  const float* pp = part + (size_t)grow * E_EXP + prt * 8;

  f32x4 s0 = {}, s1 = {};
  #pragma unroll
  for (int ks = 0; ks < KSPLIT; ++ks) {
    const float* q = pp + (size_t)ks * N_ROWS * E_EXP;
    f32x4 a = *(const f32x4*)q;
    f32x4 b = *(const f32x4*)(q + 4);
    s0 += a; s1 += b;
  }
  float lv[8] = {s0[0], s0[1], s0[2], s0[3], s1[0], s1[1], s1[2], s1[3]};

  float l1 = -3e38f, l2 = -3e38f, l3 = -3e38f;
  int   i1 = -1, i2 = -1, i3 = -1;
  auto ins = [&](float v, int e) {
    if (v > l1 || (v == l1 && e < i1)) { l3=l2; i3=i2; l2=l1; i2=i1; l1=v; i1=e; }
    else if (v > l2 || (v == l2 && e < i2)) { l3=l2; i3=i2; l2=v; i2=e; }
    else if (v > l3 || (v == l3 && e < i3)) { l3=v; i3=e; }
  };
  #pragma unroll
  for (int j = 0; j < 8; ++j) {
    int e = prt * 8 + j;
    ins(lv[j] + bias[e], e);
  }
  #pragma unroll
  for (int m = 1; m <= 8; m <<= 1) {
    float a1 = __shfl_xor(l1, m), a2 = __shfl_xor(l2, m), a3 = __shfl_xor(l3, m);
    int   b1i = __shfl_xor(i1, m), b2i = __shfl_xor(i2, m), b3i = __shfl_xor(i3, m);
    ins(a1, b1i); ins(a2, b2i); ins(a3, b3i);
  }
  if (prt == 0) {
    int fl = ((l1 - l2) < TAU) || ((l2 - l3) < TAU);
    flags[grow] = fl;
    out[(size_t)grow * 2 + 0] = 1.f / (1.f + __expf(-l1));
    out[(size_t)grow * 2 + 1] = 1.f / (1.f + __expf(-l2));
    out[(size_t)N_ROWS * 2 + (size_t)grow * 2 + 0] = (float)i1;
    out[(size_t)N_ROWS * 2 + (size_t)grow * 2 + 1] = (float)i2;
  }
}

// ---------------- kernel 2: exact f64 fixup for flagged rows (proven) ----------------
__global__ __launch_bounds__(1024) void k2_fix(
    const float* __restrict__ x, const float* __restrict__ W,
    const float* __restrict__ bias, const int* __restrict__ flags,
    float* __restrict__ out)
{
  __shared__ double lgs[E_EXP];
  const int t    = threadIdx.x;        // 1024 threads = 16 waves
  const int wvi  = t >> 6, lane = t & 63;
  const int e    = wvi * 8 + (lane >> 3);
  const int sub  = lane & 7;
  const int rbase = blockIdx.x * 8;

  for (int rr = 0; rr < 8; ++rr) {
    const int row = rbase + rr;
    if (!flags[row]) continue;
    const float* xr = x + (size_t)row * D_DIM;
    const float* wr = W + (size_t)e * D_DIM;
    double a0 = 0.0, a1 = 0.0, a2 = 0.0, a3 = 0.0;
    for (int j = 0; j < 128; ++j) {
      const int c4 = (j * 8 + sub) * 4;
      f32x4 xv = *(const f32x4*)(xr + c4);
      f32x4 wvv = *(const f32x4*)(wr + c4);
      a0 += (double)xv[0] * wvv[0];
      a1 += (double)xv[1] * wvv[1];
      a2 += (double)xv[2] * wvv[2];
      a3 += (double)xv[3] * wvv[3];
    }
    double acc = (a0 + a1) + (a2 + a3);
    #pragma unroll
    for (int m = 1; m <= 4; m <<= 1) acc += __shfl_xor(acc, m);
    if (sub == 0) lgs[e] = acc + (double)bias[e];
    __syncthreads();
    if (t == 0) {
      double l1 = -1e300, l2 = -1e300; int i1 = -1, i2 = -1;
      for (int ee = 0; ee < E_EXP; ++ee) {
        double v = lgs[ee];
        if (v > l1) { l2 = l1; i2 = i1; l1 = v; i1 = ee; }
        else if (v > l2) { l2 = v; i2 = ee; }
      }
      out[(size_t)row * 2 + 0] = (float)(1.0 / (1.0 + exp(-l1)));
      out[(size_t)row * 2 + 1] = (float)(1.0 / (1.0 + exp(-l2)));
      out[(size_t)N_ROWS * 2 + (size_t)row * 2 + 0] = (float)i1;
      out[(size_t)N_ROWS * 2 + (size_t)row * 2 + 1] = (float)i2;
    }
    __syncthreads();
  }
}

extern "C" void kernel_launch(void* const* d_in, const int* in_sizes, int n_in,
                              void* d_out, int out_size, void* d_ws, size_t ws_size,
                              hipStream_t stream) {
  const float* x  = (const float*)d_in[0];
  const float* Wm = (const float*)d_in[1];
  const float* b  = (const float*)d_in[2];
  float* out = (float*)d_out;

  uint8_t* ws = (uint8_t*)d_ws;
  uint16_t* wt    = (uint16_t*)ws;                    // 2 MiB tiled W (h+l)
  int*      flags = (int*)(ws + 2u * 1024 * 1024);    // 64 KiB
  float*    part  = (float*)(ws + 4u * 1024 * 1024);  // 16 MiB partials

  k0_split<<<dim3(256), dim3(256), 0, stream>>>(Wm, wt);
  k1_main<<<dim3((N_ROWS / BM) * KSPLIT), dim3(512), 0, stream>>>(x, wt, part);
  k3_reduce<<<dim3(N_ROWS / 32), dim3(512), 0, stream>>>(part, b, out, flags);
  k2_fix<<<dim3(N_ROWS / 8), dim3(1024), 0, stream>>>(x, Wm, b, flags, out);
}